// Round 1
// baseline (107.073 us; speedup 1.0000x reference)
//
#include <hip/hip_runtime.h>
#include <math.h>

#define C 1000
#define C4 250   // C/4, row is 4000 B = 250 float4 (16B aligned)

__device__ __forceinline__ float wave_reduce_max(float v) {
#pragma unroll
  for (int off = 32; off > 0; off >>= 1) v = fmaxf(v, __shfl_xor(v, off, 64));
  return v;
}
__device__ __forceinline__ float wave_reduce_sum(float v) {
#pragma unroll
  for (int off = 32; off > 0; off >>= 1) v += __shfl_xor(v, off, 64);
  return v;
}

// Tiled transpose of T (C x C) into At; block (0,0) thread 0 also zeroes the
// scalar result (needed for the atomic fallback path; harmless otherwise).
__global__ __launch_bounds__(256) void transpose_zero_k(
    const float* __restrict__ A, float* __restrict__ At,
    float* __restrict__ result, int do_transpose) {
  if (blockIdx.x == 0 && blockIdx.y == 0 && threadIdx.x == 0 && threadIdx.y == 0)
    *result = 0.0f;
  if (!do_transpose) return;
  __shared__ float tile[32][33];
  int x = blockIdx.x * 32 + threadIdx.x;
#pragma unroll
  for (int k = 0; k < 32; k += 8) {
    int y = blockIdx.y * 32 + threadIdx.y + k;
    if (x < C && y < C) tile[threadIdx.y + k][threadIdx.x] = A[(size_t)y * C + x];
  }
  __syncthreads();
  int xt = blockIdx.y * 32 + threadIdx.x;
#pragma unroll
  for (int k = 0; k < 32; k += 8) {
    int yt = blockIdx.x * 32 + threadIdx.y + k;
    if (xt < C && yt < C) At[(size_t)yt * C + xt] = tile[threadIdx.x][threadIdx.y + k];
  }
}

// One wave per row, 4 rows per block. beta = e_y / sum_j e_j * T[j,y]
// (softmax normalizer Z cancels between pro1 and pro2);
// ce = log(Z) - (x_y - m). Per-block partial sums -> ws (or atomic fallback).
__global__ __launch_bounds__(256) void reweight_k(
    const float* __restrict__ xin, const int* __restrict__ target,
    const float* __restrict__ Tmat, int tt_mode,
    float* __restrict__ partial, float* __restrict__ result, int B) {
  int wid = threadIdx.x >> 6;
  int lane = threadIdx.x & 63;
  int row = blockIdx.x * 4 + wid;
  float contrib = 0.0f;
  if (row < B) {
    const float4* x4 = (const float4*)(xin + (size_t)row * C);
    int y = target[row];
    float4 v[4];
    float m = -INFINITY;
#pragma unroll
    for (int k = 0; k < 4; k++) {
      int j = lane + k * 64;
      if (j < C4) {
        v[k] = x4[j];
        m = fmaxf(m, fmaxf(fmaxf(v[k].x, v[k].y), fmaxf(v[k].z, v[k].w)));
      }
    }
    m = wave_reduce_max(m);
    float se = 0.0f, st = 0.0f;
    if (tt_mode) {
      const float4* t4 = (const float4*)(Tmat + (size_t)y * C);
#pragma unroll
      for (int k = 0; k < 4; k++) {
        int j = lane + k * 64;
        if (j < C4) {
          float4 t = t4[j];
          float e0 = __expf(v[k].x - m), e1 = __expf(v[k].y - m);
          float e2 = __expf(v[k].z - m), e3 = __expf(v[k].w - m);
          se += (e0 + e1) + (e2 + e3);
          st += e0 * t.x + e1 * t.y + e2 * t.z + e3 * t.w;
        }
      }
    } else {
      // fallback: read T columns directly (uncoalesced, L2-cached)
#pragma unroll
      for (int k = 0; k < 4; k++) {
        int j = lane + k * 64;
        if (j < C4) {
          int jb = j * 4;
          float e0 = __expf(v[k].x - m), e1 = __expf(v[k].y - m);
          float e2 = __expf(v[k].z - m), e3 = __expf(v[k].w - m);
          se += (e0 + e1) + (e2 + e3);
          st += e0 * Tmat[(size_t)(jb + 0) * C + y] +
                e1 * Tmat[(size_t)(jb + 1) * C + y] +
                e2 * Tmat[(size_t)(jb + 2) * C + y] +
                e3 * Tmat[(size_t)(jb + 3) * C + y];
        }
      }
    }
    se = wave_reduce_sum(se);
    st = wave_reduce_sum(st);
    if (lane == 0) {
      float xy = xin[(size_t)row * C + y];   // L1-hot, loaded in pass 1
      float ey = __expf(xy - m);
      float ce = logf(se) - (xy - m);
      contrib = (ey / st) * ce;
    }
  }
  __shared__ float bsum[4];
  if (lane == 0) bsum[wid] = contrib;
  __syncthreads();
  if (threadIdx.x == 0) {
    float s = (bsum[0] + bsum[1]) + (bsum[2] + bsum[3]);
    if (partial) partial[blockIdx.x] = s;
    else atomicAdd(result, s);
  }
}

__global__ __launch_bounds__(256) void reduce_k(const float* __restrict__ partial,
                                                float* __restrict__ result, int n) {
  float s = 0.0f;
  for (int i = threadIdx.x; i < n; i += 256) s += partial[i];
  s = wave_reduce_sum(s);
  __shared__ float b[4];
  if ((threadIdx.x & 63) == 0) b[threadIdx.x >> 6] = s;
  __syncthreads();
  if (threadIdx.x == 0) *result = (b[0] + b[1]) + (b[2] + b[3]);
}

extern "C" void kernel_launch(void* const* d_in, const int* in_sizes, int n_in,
                              void* d_out, int out_size, void* d_ws, size_t ws_size,
                              hipStream_t stream) {
  const float* xin = (const float*)d_in[0];
  const int* target = (const int*)d_in[1];
  const float* T = (const float*)d_in[2];
  float* result = (float*)d_out;
  int B = in_sizes[1];
  int nblocks = (B + 3) / 4;

  size_t tt_bytes = (size_t)C * C * sizeof(float);           // 4,000,000 B (16B-mult)
  size_t need = tt_bytes + (size_t)nblocks * sizeof(float);

  if (ws_size >= need) {
    float* Tt = (float*)d_ws;
    float* partial = (float*)((char*)d_ws + tt_bytes);
    transpose_zero_k<<<dim3(32, 32), dim3(32, 8), 0, stream>>>(T, Tt, result, 1);
    reweight_k<<<nblocks, 256, 0, stream>>>(xin, target, Tt, 1, partial, result, B);
    reduce_k<<<1, 256, 0, stream>>>(partial, result, nblocks);
  } else {
    // workspace too small: zero result, read T columns directly, atomic combine
    transpose_zero_k<<<dim3(32, 32), dim3(32, 8), 0, stream>>>(T, nullptr, result, 0);
    reweight_k<<<nblocks, 256, 0, stream>>>(xin, target, T, 0, nullptr, result, B);
  }
}